// Round 1
// baseline (563.550 us; speedup 1.0000x reference)
//
#include <hip/hip_runtime.h>
#include <hip/hip_bf16.h>
#include <stdint.h>

#define VOCAB 50257
#define DMODEL 256
#define NROWS 2048
#define NCB 393  /* ceil(50257/128) */
#define NEGINF (-3.0e38f)

typedef short bf16x8 __attribute__((ext_vector_type(8)));
typedef float f32x4 __attribute__((ext_vector_type(4)));

// ---- threefry2x32 with key = (0,1)  [jax.random.key(1)] ----
__device__ __forceinline__ void tf2x32(uint32_t x0, uint32_t x1, uint32_t& o0, uint32_t& o1) {
  const uint32_t K0 = 0u, K1 = 1u, K2 = 0x1BD11BDBu;  // 0^1^0x1BD11BDA
  x0 += K0; x1 += K1;
#define TFR(d) { x0 += x1; x1 = (x1 << (d)) | (x1 >> (32 - (d))); x1 ^= x0; }
  TFR(13) TFR(15) TFR(26) TFR(6)
  x0 += K1; x1 += K2 + 1u;
  TFR(17) TFR(29) TFR(16) TFR(24)
  x0 += K2; x1 += K0 + 2u;
  TFR(13) TFR(15) TFR(26) TFR(6)
  x0 += K0; x1 += K1 + 3u;
  TFR(17) TFR(29) TFR(16) TFR(24)
  x0 += K1; x1 += K2 + 4u;
  TFR(13) TFR(15) TFR(26) TFR(6)
  x0 += K2; x1 += K0 + 5u;
#undef TFR
  o0 = x0; o1 = x1;
}

// jax uniform(tiny,1) -> gumbel, from the 23-bit mantissa bits
__device__ __forceinline__ float gumbel_from_bits(uint32_t b23) {
  float f = __uint_as_float(b23 | 0x3f800000u) - 1.0f;
  float u = fmaxf(f, 1.17549435e-38f);
  return -logf(-logf(u));
}

__device__ __forceinline__ unsigned short f32_to_bf16_bits(float x) {
  __hip_bfloat16 b = __float2bfloat16(x);
  return __builtin_bit_cast(unsigned short, b);
}

// ---- kernel 1: x_t = argmax_v( gumbel + log(p_t) ), one block per row ----
__global__ __launch_bounds__(256) void k_sample(const int* __restrict__ x1_arr,
                                                const float* __restrict__ t_arr,
                                                int* __restrict__ xt_out) {
  const int rr = blockIdx.x;
  const int tid = threadIdx.x;
  const int x1 = x1_arr[rr];
  const uint32_t base = (uint32_t)rr * (uint32_t)VOCAB;

  uint32_t bmax = 0u; int bidx = 0x7fffffff;  // max bits over v != x1 (first index)
  uint32_t bx1 = 0u;
  for (int v = tid; v < VOCAB; v += 256) {
    uint32_t o0, o1;
    tf2x32(0u, base + (uint32_t)v, o0, o1);   // partitionable: counter = (hi=0, lo=flat idx)
    uint32_t bits = (o0 ^ o1) >> 9;           // bits1 ^ bits2, keep 23 mantissa bits
    if (v == x1) { bx1 = bits; }
    else if (bits > bmax) { bmax = bits; bidx = v; }
  }
  __shared__ uint32_t s_max[256]; __shared__ int s_idx[256];
  __shared__ uint32_t s_bx1;
  if (tid == (x1 & 255)) s_bx1 = bx1;
  s_max[tid] = bmax; s_idx[tid] = bidx;
  __syncthreads();
  for (int off = 128; off > 0; off >>= 1) {
    if (tid < off) {
      uint32_t m2 = s_max[tid + off]; int i2 = s_idx[tid + off];
      if (m2 > s_max[tid] || (m2 == s_max[tid] && i2 < s_idx[tid])) { s_max[tid] = m2; s_idx[tid] = i2; }
    }
    __syncthreads();
  }
  if (tid == 0) {
    float tv = t_arr[rr >> 10];               // batch = rr / T
    float pmiss = (1.0f - tv) / 50257.0f;
    float Lhit = logf(tv + pmiss);
    float Lmiss = logf(pmiss);
    float A = gumbel_from_bits(s_bx1) + Lhit;
    float Bv = gumbel_from_bits(s_max[0]) + Lmiss;
    int amax = s_idx[0];
    int xt;
    if (A > Bv) xt = x1;
    else if (A == Bv) xt = (x1 < amax) ? x1 : amax;  // first-index tie like jnp.argmax
    else xt = amax;
    xt_out[rr] = xt;
  }
}

// ---- kernel 2: h_bf16[r][d] = bf16( emb[x_t[r]][d] + t_b * w_time[d] ) ----
__global__ __launch_bounds__(256) void k_h(const int* __restrict__ xt,
                                           const float* __restrict__ t_arr,
                                           const float* __restrict__ emb,
                                           const float* __restrict__ w_time,
                                           unsigned short* __restrict__ h_out) {
  const int rr = blockIdx.x, d = threadIdx.x;
  float tv = t_arr[rr >> 10];
  int e = xt[rr];
  float hv = emb[(size_t)e * DMODEL + d] + tv * w_time[d];
  h_out[rr * DMODEL + d] = f32_to_bf16_bits(hv);
}

// ---- kernel 2b: w_t[v][d] = bf16( w_out[d][v] )  (tiled transpose) ----
__global__ __launch_bounds__(256) void k_wt(const float* __restrict__ w,
                                            unsigned short* __restrict__ wt) {
  __shared__ float tile[64][65];
  const int v0 = blockIdx.x * 64;
  const int d0 = blockIdx.y * 64;
  const int tid = threadIdx.x;
  for (int i = 0; i < 16; i++) {
    int idx = i * 256 + tid;
    int dd = idx >> 6, vv = idx & 63;
    int v = v0 + vv;
    tile[dd][vv] = (v < VOCAB) ? w[(size_t)(d0 + dd) * VOCAB + v] : 0.0f;
  }
  __syncthreads();
  for (int i = 0; i < 16; i++) {
    int idx = i * 256 + tid;
    int vv = idx >> 6, dd = idx & 63;
    int v = v0 + vv;
    if (v < VOCAB) wt[(size_t)v * DMODEL + d0 + dd] = f32_to_bf16_bits(tile[dd][vv]);
  }
}

// ---- kernel 3: logits tile GEMM (bf16 MFMA) + fused per-block LSE/argmax partials ----
__global__ __launch_bounds__(256) void k_gemm(const unsigned short* __restrict__ h,
                                              const unsigned short* __restrict__ wt,
                                              const int* __restrict__ x1_arr,
                                              float* __restrict__ pm, float* __restrict__ ps,
                                              int* __restrict__ pi, float* __restrict__ tgt) {
  __shared__ union UU {
    struct { unsigned short a[128][48]; unsigned short b[128][48]; } s;  // 24 KB staging
    float out[128][129];                                                 // 66 KB logits tile
  } u;
  __shared__ float rm_[128], rs_[128]; __shared__ int ri_[128];

  const int tid = threadIdx.x;
  const int cb = blockIdx.x, rb = blockIdx.y;
  const int lane = tid & 63;
  const int wid = tid >> 6;
  const int wr = wid >> 1, wc = wid & 1;   // 2x2 wave grid, 64x64 per wave
  const int l15 = lane & 15;
  const int lk = (lane >> 4) * 8;

  f32x4 acc[4][4] = {};

  const int rstage = tid >> 2;  // 0..63
  const int part = tid & 3;

  for (int kc = 0; kc < 8; kc++) {
    const int ko = kc * 32 + part * 8;
#pragma unroll
    for (int rr = rstage; rr < 128; rr += 64) {
      uint4 va = *reinterpret_cast<const uint4*>(h + ((size_t)(rb * 128 + rr) * DMODEL + ko));
      *reinterpret_cast<uint4*>(&u.s.a[rr][part * 8]) = va;
    }
#pragma unroll
    for (int cc = rstage; cc < 128; cc += 64) {
      int cg = cb * 128 + cc;
      uint4 vb = make_uint4(0u, 0u, 0u, 0u);
      if (cg < VOCAB) vb = *reinterpret_cast<const uint4*>(wt + ((size_t)cg * DMODEL + ko));
      *reinterpret_cast<uint4*>(&u.s.b[cc][part * 8]) = vb;
    }
    __syncthreads();
    bf16x8 af[4], bf[4];
#pragma unroll
    for (int mi = 0; mi < 4; mi++)
      af[mi] = *reinterpret_cast<const bf16x8*>(&u.s.a[wr * 64 + mi * 16 + l15][lk]);
#pragma unroll
    for (int ni = 0; ni < 4; ni++)
      bf[ni] = *reinterpret_cast<const bf16x8*>(&u.s.b[wc * 64 + ni * 16 + l15][lk]);
#pragma unroll
    for (int mi = 0; mi < 4; mi++)
#pragma unroll
      for (int ni = 0; ni < 4; ni++)
        acc[mi][ni] = __builtin_amdgcn_mfma_f32_16x16x32_bf16(af[mi], bf[ni], acc[mi][ni], 0, 0, 0);
    __syncthreads();
  }

  // spill logits tile to LDS (C/D layout: col = lane&15, row = (lane>>4)*4 + q)
  const int lg = lane >> 4;
#pragma unroll
  for (int mi = 0; mi < 4; mi++)
#pragma unroll
    for (int ni = 0; ni < 4; ni++) {
      int col = wc * 64 + ni * 16 + l15;
      int rbase = wr * 64 + mi * 16 + lg * 4;
#pragma unroll
      for (int q = 0; q < 4; q++) u.out[rbase + q][col] = acc[mi][ni][q];
    }
  __syncthreads();

  // per-row online max / sum-exp / argmax over this block's 128 cols
  const int row = tid >> 1, half = tid & 1;
  const int colbase = cb * 128;
  const int nvalid = min(128, VOCAB - colbase);
  float m = NEGINF, s = 0.0f; int amx = 0x7fffffff;
  const int c0 = half * 64;
  const int c1 = min(c0 + 64, nvalid);
  for (int c = c0; c < c1; c++) {
    float x = u.out[row][c];
    if (x > m) { s = s * __expf(m - x) + 1.0f; m = x; amx = c; }
    else s += __expf(x - m);
  }
  if (half == 1) { rm_[row] = m; rs_[row] = s; ri_[row] = amx; }
  __syncthreads();
  if (half == 0) {
    float m2 = rm_[row], s2 = rs_[row]; int i2 = ri_[row];
    float M = fmaxf(m, m2);
    float S = s * __expf(m - M) + s2 * __expf(m2 - M);
    int idx = (m >= m2) ? amx : i2;  // half0 has lower cols -> first-index ties
    int rowg = rb * 128 + row;
    size_t pidx = (size_t)rowg * NCB + cb;
    pm[pidx] = M; ps[pidx] = S; pi[pidx] = colbase + idx;
    int x1 = x1_arr[rowg];
    int loc = x1 - colbase;
    if (loc >= 0 && loc < nvalid) tgt[rowg] = u.out[row][loc];
  }
}

// ---- kernel 4a: combine NCB partials per row -> nll + hit ----
__global__ __launch_bounds__(256) void k_rowreduce(const float* __restrict__ pm,
                                                   const float* __restrict__ ps,
                                                   const int* __restrict__ pi,
                                                   const float* __restrict__ tgt,
                                                   const int* __restrict__ x1_arr,
                                                   float* __restrict__ rownll,
                                                   float* __restrict__ rowhit) {
  const int row = blockIdx.x, tid = threadIdx.x;
  float M = NEGINF, S = 0.0f; int best = 0x7fffffff;
  for (int cbk = tid; cbk < NCB; cbk += 256) {
    size_t pidx = (size_t)row * NCB + cbk;
    float m = pm[pidx], sv = ps[pidx]; int idx = pi[pidx];
    if (m > M) { S = S * __expf(M - m) + sv; M = m; best = idx; }
    else if (m == M) { S += sv; if (idx < best) best = idx; }
    else S += sv * __expf(m - M);
  }
  __shared__ float sm_[256], ss_[256]; __shared__ int si_[256];
  sm_[tid] = M; ss_[tid] = S; si_[tid] = best;
  __syncthreads();
  for (int off = 128; off > 0; off >>= 1) {
    if (tid < off) {
      float m2 = sm_[tid + off], s2 = ss_[tid + off]; int i2 = si_[tid + off];
      float M1 = sm_[tid], S1 = ss_[tid]; int b1 = si_[tid];
      float Mn = fmaxf(M1, m2);
      float Sn = S1 * __expf(M1 - Mn) + s2 * __expf(m2 - Mn);
      int bn = (M1 > m2) ? b1 : ((m2 > M1) ? i2 : ((b1 < i2) ? b1 : i2));
      sm_[tid] = Mn; ss_[tid] = Sn; si_[tid] = bn;
    }
    __syncthreads();
  }
  if (tid == 0) {
    float nll = sm_[0] + logf(ss_[0]) - tgt[row];
    rownll[row] = nll;
    rowhit[row] = (si_[0] == x1_arr[row]) ? 1.0f : 0.0f;
  }
}

// ---- kernel 4b: final means ----
__global__ __launch_bounds__(1024) void k_final(const float* __restrict__ rownll,
                                                const float* __restrict__ rowhit,
                                                float* __restrict__ out) {
  const int tid = threadIdx.x;
  float l = rownll[tid] + rownll[tid + 1024];
  float a = rowhit[tid] + rowhit[tid + 1024];
  __shared__ float sl[1024], sa[1024];
  sl[tid] = l; sa[tid] = a;
  __syncthreads();
  for (int off = 512; off > 0; off >>= 1) {
    if (tid < off) { sl[tid] += sl[tid + off]; sa[tid] += sa[tid + off]; }
    __syncthreads();
  }
  if (tid == 0) { out[0] = sl[0] * (1.0f / 2048.0f); out[1] = sa[0] * (1.0f / 2048.0f); }
}

extern "C" void kernel_launch(void* const* d_in, const int* in_sizes, int n_in,
                              void* d_out, int out_size, void* d_ws, size_t ws_size,
                              hipStream_t stream) {
  const int* x1 = (const int*)d_in[0];
  const float* t = (const float*)d_in[1];
  const float* emb = (const float*)d_in[2];
  const float* w_time = (const float*)d_in[3];
  const float* w_out = (const float*)d_in[4];
  float* out = (float*)d_out;

  char* ws = (char*)d_ws;
  int* xt = (int*)ws;                                              // 8 KB
  unsigned short* h = (unsigned short*)(ws + 8192);                // 1 MB
  unsigned short* wt = (unsigned short*)(ws + 8192 + 1048576);     // 25.73 MB
  size_t off = 8192 + 1048576 + (size_t)VOCAB * DMODEL * 2;        // 26,788,352
  float* pm = (float*)(ws + off);  off += (size_t)NROWS * NCB * 4;
  float* ps = (float*)(ws + off);  off += (size_t)NROWS * NCB * 4;
  int*   pi = (int*)(ws + off);    off += (size_t)NROWS * NCB * 4;
  float* tgt = (float*)(ws + off); off += NROWS * 4;
  float* rownll = (float*)(ws + off); off += NROWS * 4;
  float* rowhit = (float*)(ws + off); off += NROWS * 4;

  dim3 b256(256);
  k_sample<<<dim3(NROWS), b256, 0, stream>>>(x1, t, xt);
  k_h<<<dim3(NROWS), b256, 0, stream>>>(xt, t, emb, w_time, h);
  k_wt<<<dim3(786, 4), b256, 0, stream>>>(w_out, wt);
  k_gemm<<<dim3(NCB, 16), b256, 0, stream>>>(h, wt, x1, pm, ps, pi, tgt);
  k_rowreduce<<<dim3(NROWS), b256, 0, stream>>>(pm, ps, pi, tgt, x1, rownll, rowhit);
  k_final<<<dim3(1), dim3(1024), 0, stream>>>(rownll, rowhit, out);
}

// Round 2
// 489.614 us; speedup vs baseline: 1.1510x; 1.1510x over previous
//
#include <hip/hip_runtime.h>
#include <hip/hip_bf16.h>
#include <stdint.h>

#define VOCAB 50257
#define DMODEL 256
#define NROWS 2048
#define NCB 393  /* ceil(50257/128) */
#define NEGINF (-3.0e38f)

typedef short bf16x8 __attribute__((ext_vector_type(8)));
typedef float f32x4 __attribute__((ext_vector_type(4)));

__device__ __forceinline__ uint32_t rotl32(uint32_t x, int d) {
  return __builtin_amdgcn_alignbit(x, x, (uint32_t)(32 - d));  // v_alignbit_b32: rotr(x,32-d)=rotl(x,d)
}

// ---- threefry2x32 with key = (0,1)  [jax.random.key(1)] ----
__device__ __forceinline__ void tf2x32(uint32_t x0, uint32_t x1, uint32_t& o0, uint32_t& o1) {
  const uint32_t K0 = 0u, K1 = 1u, K2 = 0x1BD11BDBu;  // 0^1^0x1BD11BDA
  x0 += K0; x1 += K1;
#define TFR(d) { x0 += x1; x1 = rotl32(x1, d); x1 ^= x0; }
  TFR(13) TFR(15) TFR(26) TFR(6)
  x0 += K1; x1 += K2 + 1u;
  TFR(17) TFR(29) TFR(16) TFR(24)
  x0 += K2; x1 += K0 + 2u;
  TFR(13) TFR(15) TFR(26) TFR(6)
  x0 += K0; x1 += K1 + 3u;
  TFR(17) TFR(29) TFR(16) TFR(24)
  x0 += K1; x1 += K2 + 4u;
  TFR(13) TFR(15) TFR(26) TFR(6)
  x0 += K2; x1 += K0 + 5u;
#undef TFR
  o0 = x0; o1 = x1;
}

// jax uniform(tiny,1) -> gumbel, from the 23-bit mantissa bits
__device__ __forceinline__ float gumbel_from_bits(uint32_t b23) {
  float f = __uint_as_float(b23 | 0x3f800000u) - 1.0f;
  float u = fmaxf(f, 1.17549435e-38f);
  return -logf(-logf(u));
}

__device__ __forceinline__ unsigned short f32_to_bf16_bits(float x) {
  __hip_bfloat16 b = __float2bfloat16(x);
  return __builtin_bit_cast(unsigned short, b);
}

// ---- kernel 1: x_t = argmax_v( gumbel + log(p_t) ), one block per row ----
// packed = (rawbits & ~0x1FF) | (511 - it): order = (bits desc, it asc) so a
// single u32 max gives argmax with first-index tie-break within a lane.
__global__ __launch_bounds__(256) void k_sample(const int* __restrict__ x1_arr,
                                                const float* __restrict__ t_arr,
                                                int* __restrict__ xt_out) {
  const int rr = blockIdx.x;
  const int tid = threadIdx.x;
  const int x1 = x1_arr[rr];
  const uint32_t base = (uint32_t)rr * (uint32_t)VOCAB;
  const int it_x1 = x1 >> 8;       // wave-uniform
  const int lane_x1 = x1 & 255;

  const uint32_t ctr0 = base + (uint32_t)tid;
  uint32_t pmax = 0u;              // real packed >= 315 > 0 always
  const int FULL = VOCAB >> 8;     // 196
  for (int it = 0; it < FULL; ++it) {
    uint32_t o0, o1;
    tf2x32(0u, ctr0 + (uint32_t)(it << 8), o0, o1);
    uint32_t packed = ((o0 ^ o1) & 0xFFFFFE00u) | (uint32_t)(511 - it);
    if (it == it_x1) {                       // uniform scalar branch (once)
      if (tid == lane_x1) packed = 0u;       // exclude v == x1
    }
    pmax = max(pmax, packed);
  }
  {  // tail: it = 196, v = 50176 + tid, valid for tid < 81
    const int it = FULL;
    if (tid < (VOCAB - FULL * 256)) {
      uint32_t o0, o1;
      tf2x32(0u, ctr0 + (uint32_t)(it << 8), o0, o1);
      uint32_t packed = ((o0 ^ o1) & 0xFFFFFE00u) | (uint32_t)(511 - it);
      if (it == it_x1 && tid == lane_x1) packed = 0u;
      pmax = max(pmax, packed);
    }
  }

  __shared__ uint32_t s_p[256]; __shared__ int s_t[256];
  s_p[tid] = pmax; s_t[tid] = tid;
  __syncthreads();
  for (int off = 128; off > 0; off >>= 1) {
    if (tid < off) {
      uint32_t p2 = s_p[tid + off]; int t2 = s_t[tid + off];
      if (p2 > s_p[tid] || (p2 == s_p[tid] && t2 < s_t[tid])) { s_p[tid] = p2; s_t[tid] = t2; }
    }
    __syncthreads();
  }
  if (tid == 0) {
    const uint32_t packed = s_p[0];
    const uint32_t bmax = packed >> 9;                    // 23-bit bits of the miss-max
    const int amax = ((511 - (int)(packed & 0x1FFu)) << 8) + s_t[0];
    uint32_t o0, o1;
    tf2x32(0u, base + (uint32_t)x1, o0, o1);
    const uint32_t bx1 = (o0 ^ o1) >> 9;
    float tv = t_arr[rr >> 10];               // batch = rr / T
    float pmiss = (1.0f - tv) / 50257.0f;
    float Lhit = logf(tv + pmiss);
    float Lmiss = logf(pmiss);
    float A = gumbel_from_bits(bx1) + Lhit;
    float Bv = gumbel_from_bits(bmax) + Lmiss;
    int xt;
    if (A > Bv) xt = x1;
    else if (A == Bv) xt = (x1 < amax) ? x1 : amax;  // first-index tie like jnp.argmax
    else xt = amax;
    xt_out[rr] = xt;
  }
}

// ---- kernel 2: h_bf16[r][d] = bf16( emb[x_t[r]][d] + t_b * w_time[d] ) ----
__global__ __launch_bounds__(256) void k_h(const int* __restrict__ xt,
                                           const float* __restrict__ t_arr,
                                           const float* __restrict__ emb,
                                           const float* __restrict__ w_time,
                                           unsigned short* __restrict__ h_out) {
  const int rr = blockIdx.x, d = threadIdx.x;
  float tv = t_arr[rr >> 10];
  int e = xt[rr];
  float hv = emb[(size_t)e * DMODEL + d] + tv * w_time[d];
  h_out[rr * DMODEL + d] = f32_to_bf16_bits(hv);
}

// ---- kernel 2b: w_t[v][d] = bf16( w_out[d][v] )  (tiled transpose) ----
__global__ __launch_bounds__(256) void k_wt(const float* __restrict__ w,
                                            unsigned short* __restrict__ wt) {
  __shared__ float tile[64][65];
  const int v0 = blockIdx.x * 64;
  const int d0 = blockIdx.y * 64;
  const int tid = threadIdx.x;
  for (int i = 0; i < 16; i++) {
    int idx = i * 256 + tid;
    int dd = idx >> 6, vv = idx & 63;
    int v = v0 + vv;
    tile[dd][vv] = (v < VOCAB) ? w[(size_t)(d0 + dd) * VOCAB + v] : 0.0f;
  }
  __syncthreads();
  for (int i = 0; i < 16; i++) {
    int idx = i * 256 + tid;
    int vv = idx >> 6, dd = idx & 63;
    int v = v0 + vv;
    if (v < VOCAB) wt[(size_t)v * DMODEL + d0 + dd] = f32_to_bf16_bits(tile[dd][vv]);
  }
}

// ---- kernel 3: logits tile GEMM (bf16 MFMA) + fused per-block LSE/argmax partials ----
__global__ __launch_bounds__(256) void k_gemm(const unsigned short* __restrict__ h,
                                              const unsigned short* __restrict__ wt,
                                              const int* __restrict__ x1_arr,
                                              float* __restrict__ pm, float* __restrict__ ps,
                                              int* __restrict__ pi, float* __restrict__ tgt) {
  __shared__ union UU {
    struct { unsigned short a[128][48]; unsigned short b[128][48]; } s;  // 24 KB staging
    float out[128][129];                                                 // 66 KB logits tile
  } u;
  __shared__ float rm_[128], rs_[128]; __shared__ int ri_[128];

  const int tid = threadIdx.x;
  const int cb = blockIdx.x, rb = blockIdx.y;
  const int lane = tid & 63;
  const int wid = tid >> 6;
  const int wr = wid >> 1, wc = wid & 1;   // 2x2 wave grid, 64x64 per wave
  const int l15 = lane & 15;
  const int lk = (lane >> 4) * 8;

  f32x4 acc[4][4] = {};

  const int rstage = tid >> 2;  // 0..63
  const int part = tid & 3;

  for (int kc = 0; kc < 8; kc++) {
    const int ko = kc * 32 + part * 8;
#pragma unroll
    for (int rr = rstage; rr < 128; rr += 64) {
      uint4 va = *reinterpret_cast<const uint4*>(h + ((size_t)(rb * 128 + rr) * DMODEL + ko));
      *reinterpret_cast<uint4*>(&u.s.a[rr][part * 8]) = va;
    }
#pragma unroll
    for (int cc = rstage; cc < 128; cc += 64) {
      int cg = cb * 128 + cc;
      uint4 vb = make_uint4(0u, 0u, 0u, 0u);
      if (cg < VOCAB) vb = *reinterpret_cast<const uint4*>(wt + ((size_t)cg * DMODEL + ko));
      *reinterpret_cast<uint4*>(&u.s.b[cc][part * 8]) = vb;
    }
    __syncthreads();
    bf16x8 af[4], bf[4];
#pragma unroll
    for (int mi = 0; mi < 4; mi++)
      af[mi] = *reinterpret_cast<const bf16x8*>(&u.s.a[wr * 64 + mi * 16 + l15][lk]);
#pragma unroll
    for (int ni = 0; ni < 4; ni++)
      bf[ni] = *reinterpret_cast<const bf16x8*>(&u.s.b[wc * 64 + ni * 16 + l15][lk]);
#pragma unroll
    for (int mi = 0; mi < 4; mi++)
#pragma unroll
      for (int ni = 0; ni < 4; ni++)
        acc[mi][ni] = __builtin_amdgcn_mfma_f32_16x16x32_bf16(af[mi], bf[ni], acc[mi][ni], 0, 0, 0);
    __syncthreads();
  }

  // spill logits tile to LDS (C/D layout: col = lane&15, row = (lane>>4)*4 + q)
  const int lg = lane >> 4;
#pragma unroll
  for (int mi = 0; mi < 4; mi++)
#pragma unroll
    for (int ni = 0; ni < 4; ni++) {
      int col = wc * 64 + ni * 16 + l15;
      int rbase = wr * 64 + mi * 16 + lg * 4;
#pragma unroll
      for (int q = 0; q < 4; q++) u.out[rbase + q][col] = acc[mi][ni][q];
    }
  __syncthreads();

  // per-row online max / sum-exp / argmax over this block's 128 cols
  const int row = tid >> 1, half = tid & 1;
  const int colbase = cb * 128;
  const int nvalid = min(128, VOCAB - colbase);
  float m = NEGINF, s = 0.0f; int amx = 0x7fffffff;
  const int c0 = half * 64;
  const int c1 = min(c0 + 64, nvalid);
  for (int c = c0; c < c1; c++) {
    float x = u.out[row][c];
    if (x > m) { s = s * __expf(m - x) + 1.0f; m = x; amx = c; }
    else s += __expf(x - m);
  }
  if (half == 1) { rm_[row] = m; rs_[row] = s; ri_[row] = amx; }
  __syncthreads();
  if (half == 0) {
    float m2 = rm_[row], s2 = rs_[row]; int i2 = ri_[row];
    float M = fmaxf(m, m2);
    float S = s * __expf(m - M) + s2 * __expf(m2 - M);
    int idx = (m >= m2) ? amx : i2;  // half0 has lower cols -> first-index ties
    int rowg = rb * 128 + row;
    size_t pidx = (size_t)rowg * NCB + cb;
    pm[pidx] = M; ps[pidx] = S; pi[pidx] = colbase + idx;
    int x1 = x1_arr[rowg];
    int loc = x1 - colbase;
    if (loc >= 0 && loc < nvalid) tgt[rowg] = u.out[row][loc];
  }
}

// ---- kernel 4a: combine NCB partials per row -> nll + hit ----
__global__ __launch_bounds__(256) void k_rowreduce(const float* __restrict__ pm,
                                                   const float* __restrict__ ps,
                                                   const int* __restrict__ pi,
                                                   const float* __restrict__ tgt,
                                                   const int* __restrict__ x1_arr,
                                                   float* __restrict__ rownll,
                                                   float* __restrict__ rowhit) {
  const int row = blockIdx.x, tid = threadIdx.x;
  float M = NEGINF, S = 0.0f; int best = 0x7fffffff;
  for (int cbk = tid; cbk < NCB; cbk += 256) {
    size_t pidx = (size_t)row * NCB + cbk;
    float m = pm[pidx], sv = ps[pidx]; int idx = pi[pidx];
    if (m > M) { S = S * __expf(M - m) + sv; M = m; best = idx; }
    else if (m == M) { S += sv; if (idx < best) best = idx; }
    else S += sv * __expf(m - M);
  }
  __shared__ float sm_[256], ss_[256]; __shared__ int si_[256];
  sm_[tid] = M; ss_[tid] = S; si_[tid] = best;
  __syncthreads();
  for (int off = 128; off > 0; off >>= 1) {
    if (tid < off) {
      float m2 = sm_[tid + off], s2 = ss_[tid + off]; int i2 = si_[tid + off];
      float M1 = sm_[tid], S1 = ss_[tid]; int b1 = si_[tid];
      float Mn = fmaxf(M1, m2);
      float Sn = S1 * __expf(M1 - Mn) + s2 * __expf(m2 - Mn);
      int bn = (M1 > m2) ? b1 : ((m2 > M1) ? i2 : ((b1 < i2) ? b1 : i2));
      sm_[tid] = Mn; ss_[tid] = Sn; si_[tid] = bn;
    }
    __syncthreads();
  }
  if (tid == 0) {
    float nll = sm_[0] + logf(ss_[0]) - tgt[row];
    rownll[row] = nll;
    rowhit[row] = (si_[0] == x1_arr[row]) ? 1.0f : 0.0f;
  }
}

// ---- kernel 4b: final means ----
__global__ __launch_bounds__(1024) void k_final(const float* __restrict__ rownll,
                                                const float* __restrict__ rowhit,
                                                float* __restrict__ out) {
  const int tid = threadIdx.x;
  float l = rownll[tid] + rownll[tid + 1024];
  float a = rowhit[tid] + rowhit[tid + 1024];
  __shared__ float sl[1024], sa[1024];
  sl[tid] = l; sa[tid] = a;
  __syncthreads();
  for (int off = 512; off > 0; off >>= 1) {
    if (tid < off) { sl[tid] += sl[tid + off]; sa[tid] += sa[tid + off]; }
    __syncthreads();
  }
  if (tid == 0) { out[0] = sl[0] * (1.0f / 2048.0f); out[1] = sa[0] * (1.0f / 2048.0f); }
}

extern "C" void kernel_launch(void* const* d_in, const int* in_sizes, int n_in,
                              void* d_out, int out_size, void* d_ws, size_t ws_size,
                              hipStream_t stream) {
  const int* x1 = (const int*)d_in[0];
  const float* t = (const float*)d_in[1];
  const float* emb = (const float*)d_in[2];
  const float* w_time = (const float*)d_in[3];
  const float* w_out = (const float*)d_in[4];
  float* out = (float*)d_out;

  char* ws = (char*)d_ws;
  int* xt = (int*)ws;                                              // 8 KB
  unsigned short* h = (unsigned short*)(ws + 8192);                // 1 MB
  unsigned short* wt = (unsigned short*)(ws + 8192 + 1048576);     // 25.73 MB
  size_t off = 8192 + 1048576 + (size_t)VOCAB * DMODEL * 2;        // 26,788,352
  float* pm = (float*)(ws + off);  off += (size_t)NROWS * NCB * 4;
  float* ps = (float*)(ws + off);  off += (size_t)NROWS * NCB * 4;
  int*   pi = (int*)(ws + off);    off += (size_t)NROWS * NCB * 4;
  float* tgt = (float*)(ws + off); off += NROWS * 4;
  float* rownll = (float*)(ws + off); off += NROWS * 4;
  float* rowhit = (float*)(ws + off); off += NROWS * 4;

  dim3 b256(256);
  k_sample<<<dim3(NROWS), b256, 0, stream>>>(x1, t, xt);
  k_h<<<dim3(NROWS), b256, 0, stream>>>(xt, t, emb, w_time, h);
  k_wt<<<dim3(786, 4), b256, 0, stream>>>(w_out, wt);
  k_gemm<<<dim3(NCB, 16), b256, 0, stream>>>(h, wt, x1, pm, ps, pi, tgt);
  k_rowreduce<<<dim3(NROWS), b256, 0, stream>>>(pm, ps, pi, tgt, x1, rownll, rowhit);
  k_final<<<dim3(1), dim3(1024), 0, stream>>>(rownll, rowhit, out);
}

// Round 3
// 378.639 us; speedup vs baseline: 1.4884x; 1.2931x over previous
//
#include <hip/hip_runtime.h>
#include <hip/hip_bf16.h>
#include <stdint.h>

#define VOCAB 50257
#define DMODEL 256
#define NROWS 2048
#define NCB 393  /* ceil(50257/128) */
#define NEGINF (-3.0e38f)

typedef short bf16x8 __attribute__((ext_vector_type(8)));
typedef float f32x4 __attribute__((ext_vector_type(4)));

__device__ __forceinline__ uint32_t rotl32(uint32_t x, int d) {
  return __builtin_amdgcn_alignbit(x, x, (uint32_t)(32 - d));  // v_alignbit_b32: rotr(x,32-d)=rotl(x,d)
}

// ---- threefry2x32 with key = (0,1)  [jax.random.key(1)] ----
__device__ __forceinline__ void tf2x32(uint32_t x0, uint32_t x1, uint32_t& o0, uint32_t& o1) {
  const uint32_t K0 = 0u, K1 = 1u, K2 = 0x1BD11BDBu;  // 0^1^0x1BD11BDA
  x0 += K0; x1 += K1;
#define TFR(d) { x0 += x1; x1 = rotl32(x1, d); x1 ^= x0; }
  TFR(13) TFR(15) TFR(26) TFR(6)
  x0 += K1; x1 += K2 + 1u;
  TFR(17) TFR(29) TFR(16) TFR(24)
  x0 += K2; x1 += K0 + 2u;
  TFR(13) TFR(15) TFR(26) TFR(6)
  x0 += K0; x1 += K1 + 3u;
  TFR(17) TFR(29) TFR(16) TFR(24)
  x0 += K1; x1 += K2 + 4u;
  TFR(13) TFR(15) TFR(26) TFR(6)
  x0 += K2; x1 += K0 + 5u;
#undef TFR
  o0 = x0; o1 = x1;
}

// jax uniform(tiny,1) -> gumbel, from the 23-bit mantissa bits
__device__ __forceinline__ float gumbel_from_bits(uint32_t b23) {
  float f = __uint_as_float(b23 | 0x3f800000u) - 1.0f;
  float u = fmaxf(f, 1.17549435e-38f);
  return -logf(-logf(u));
}

__device__ __forceinline__ unsigned short f32_to_bf16_bits(float x) {
  __hip_bfloat16 b = __float2bfloat16(x);
  return __builtin_bit_cast(unsigned short, b);
}

// ---- kernel 1: x_t = argmax_v( gumbel + log(p_t) ), one block per row ----
__global__ __launch_bounds__(256) void k_sample(const int* __restrict__ x1_arr,
                                                const float* __restrict__ t_arr,
                                                int* __restrict__ xt_out) {
  const int rr = blockIdx.x;
  const int tid = threadIdx.x;
  const int x1 = x1_arr[rr];
  const uint32_t base = (uint32_t)rr * (uint32_t)VOCAB;
  const int it_x1 = x1 >> 8;       // wave-uniform
  const int lane_x1 = x1 & 255;

  const uint32_t ctr0 = base + (uint32_t)tid;
  uint32_t pmax = 0u;              // real packed >= 315 > 0 always
  const int FULL = VOCAB >> 8;     // 196
  for (int it = 0; it < FULL; ++it) {
    uint32_t o0, o1;
    tf2x32(0u, ctr0 + (uint32_t)(it << 8), o0, o1);
    uint32_t packed = ((o0 ^ o1) & 0xFFFFFE00u) | (uint32_t)(511 - it);
    if (it == it_x1) {                       // uniform scalar branch (once)
      if (tid == lane_x1) packed = 0u;       // exclude v == x1
    }
    pmax = max(pmax, packed);
  }
  {  // tail: it = 196, v = 50176 + tid, valid for tid < 81
    const int it = FULL;
    if (tid < (VOCAB - FULL * 256)) {
      uint32_t o0, o1;
      tf2x32(0u, ctr0 + (uint32_t)(it << 8), o0, o1);
      uint32_t packed = ((o0 ^ o1) & 0xFFFFFE00u) | (uint32_t)(511 - it);
      if (it == it_x1 && tid == lane_x1) packed = 0u;
      pmax = max(pmax, packed);
    }
  }

  __shared__ uint32_t s_p[256]; __shared__ int s_t[256];
  s_p[tid] = pmax; s_t[tid] = tid;
  __syncthreads();
  for (int off = 128; off > 0; off >>= 1) {
    if (tid < off) {
      uint32_t p2 = s_p[tid + off]; int t2 = s_t[tid + off];
      if (p2 > s_p[tid] || (p2 == s_p[tid] && t2 < s_t[tid])) { s_p[tid] = p2; s_t[tid] = t2; }
    }
    __syncthreads();
  }
  if (tid == 0) {
    const uint32_t packed = s_p[0];
    const uint32_t bmax = packed >> 9;                    // 23-bit bits of the miss-max
    const int amax = ((511 - (int)(packed & 0x1FFu)) << 8) + s_t[0];
    uint32_t o0, o1;
    tf2x32(0u, base + (uint32_t)x1, o0, o1);
    const uint32_t bx1 = (o0 ^ o1) >> 9;
    float tv = t_arr[rr >> 10];               // batch = rr / T
    float pmiss = (1.0f - tv) / 50257.0f;
    float Lhit = logf(tv + pmiss);
    float Lmiss = logf(pmiss);
    float A = gumbel_from_bits(bx1) + Lhit;
    float Bv = gumbel_from_bits(bmax) + Lmiss;
    int xt;
    if (A > Bv) xt = x1;
    else if (A == Bv) xt = (x1 < amax) ? x1 : amax;  // first-index tie like jnp.argmax
    else xt = amax;
    xt_out[rr] = xt;
  }
}

// ---- kernel 2: h_bf16[r][d] = bf16( emb[x_t[r]][d] + t_b * w_time[d] ) ----
__global__ __launch_bounds__(256) void k_h(const int* __restrict__ xt,
                                           const float* __restrict__ t_arr,
                                           const float* __restrict__ emb,
                                           const float* __restrict__ w_time,
                                           unsigned short* __restrict__ h_out) {
  const int rr = blockIdx.x, d = threadIdx.x;
  float tv = t_arr[rr >> 10];
  int e = xt[rr];
  float hv = emb[(size_t)e * DMODEL + d] + tv * w_time[d];
  h_out[rr * DMODEL + d] = f32_to_bf16_bits(hv);
}

// ---- kernel 2b: w_t[v][d] = bf16( w_out[d][v] )  (tiled transpose) ----
__global__ __launch_bounds__(256) void k_wt(const float* __restrict__ w,
                                            unsigned short* __restrict__ wt) {
  __shared__ float tile[64][65];
  const int v0 = blockIdx.x * 64;
  const int d0 = blockIdx.y * 64;
  const int tid = threadIdx.x;
  for (int i = 0; i < 16; i++) {
    int idx = i * 256 + tid;
    int dd = idx >> 6, vv = idx & 63;
    int v = v0 + vv;
    tile[dd][vv] = (v < VOCAB) ? w[(size_t)(d0 + dd) * VOCAB + v] : 0.0f;
  }
  __syncthreads();
  for (int i = 0; i < 16; i++) {
    int idx = i * 256 + tid;
    int vv = idx >> 6, dd = idx & 63;
    int v = v0 + vv;
    if (v < VOCAB) wt[(size_t)v * DMODEL + d0 + dd] = f32_to_bf16_bits(tile[dd][vv]);
  }
}

// ---- kernel 3: logits tile GEMM (bf16 MFMA) + register-resident fused LSE/argmax ----
// grid(16 rb fast, 393 cb slow): blocks sharing a B-panel are concurrent; h stays L2-hot.
__global__ __launch_bounds__(256) void k_gemm(const unsigned short* __restrict__ h,
                                              const unsigned short* __restrict__ wt,
                                              const int* __restrict__ x1_arr,
                                              float* __restrict__ pm, float* __restrict__ ps,
                                              int* __restrict__ pi, float* __restrict__ tgt) {
  __shared__ unsigned short sa[128][40];  // stride 40 shorts = 20 banks -> uniform groups
  __shared__ unsigned short sb[128][40];
  __shared__ float rm_[128][2], rs_[128][2]; __shared__ int ri_[128][2];
  __shared__ int sx1[128];

  const int tid = threadIdx.x;
  const int rb = blockIdx.x, cb = blockIdx.y;
  const int lane = tid & 63;
  const int wid = tid >> 6;
  const int wr = wid >> 1, wc = wid & 1;   // 2x2 wave grid, 64x64 per wave
  const int l15 = lane & 15;
  const int lg = lane >> 4;
  const int lk = lg * 8;

  if (tid < 128) sx1[tid] = x1_arr[rb * 128 + tid];

  f32x4 acc[4][4] = {};

  const int rstage = tid >> 2;  // 0..63
  const int part = tid & 3;
  const unsigned short* aptr = h + ((size_t)(rb * 128 + rstage) * DMODEL + part * 8);
  const int cg0 = cb * 128 + rstage;

  uint4 pa0, pa1, pb0, pb1;
  {
    pa0 = *reinterpret_cast<const uint4*>(aptr);
    pa1 = *reinterpret_cast<const uint4*>(aptr + 64 * DMODEL);
    pb0 = make_uint4(0u, 0u, 0u, 0u); pb1 = make_uint4(0u, 0u, 0u, 0u);
    if (cg0 < VOCAB)      pb0 = *reinterpret_cast<const uint4*>(wt + ((size_t)cg0 * DMODEL + part * 8));
    if (cg0 + 64 < VOCAB) pb1 = *reinterpret_cast<const uint4*>(wt + ((size_t)(cg0 + 64) * DMODEL + part * 8));
  }

  for (int kc = 0; kc < 8; kc++) {
    *reinterpret_cast<uint4*>(&sa[rstage][part * 8]) = pa0;
    *reinterpret_cast<uint4*>(&sa[rstage + 64][part * 8]) = pa1;
    *reinterpret_cast<uint4*>(&sb[rstage][part * 8]) = pb0;
    *reinterpret_cast<uint4*>(&sb[rstage + 64][part * 8]) = pb1;
    __syncthreads();

    // prefetch next K-step ((kc+1)&7 wraps harmlessly on the last iter)
    {
      const int kn = (kc + 1) & 7;
      const int ko = kn * 32 + part * 8;
      pa0 = *reinterpret_cast<const uint4*>(aptr + (ko - part * 8) + part * 8 + (kn ? kn * 32 - kn * 32 : 0));
      pa0 = *reinterpret_cast<const uint4*>(h + ((size_t)(rb * 128 + rstage) * DMODEL + ko));
      pa1 = *reinterpret_cast<const uint4*>(h + ((size_t)(rb * 128 + rstage + 64) * DMODEL + ko));
      pb0 = make_uint4(0u, 0u, 0u, 0u); pb1 = make_uint4(0u, 0u, 0u, 0u);
      if (cg0 < VOCAB)      pb0 = *reinterpret_cast<const uint4*>(wt + ((size_t)cg0 * DMODEL + ko));
      if (cg0 + 64 < VOCAB) pb1 = *reinterpret_cast<const uint4*>(wt + ((size_t)(cg0 + 64) * DMODEL + ko));
    }

    bf16x8 af[4], bfr[4];
#pragma unroll
    for (int mi = 0; mi < 4; mi++)
      af[mi] = *reinterpret_cast<const bf16x8*>(&sa[wr * 64 + mi * 16 + l15][lk]);
#pragma unroll
    for (int ni = 0; ni < 4; ni++)
      bfr[ni] = *reinterpret_cast<const bf16x8*>(&sb[wc * 64 + ni * 16 + l15][lk]);
#pragma unroll
    for (int mi = 0; mi < 4; mi++)
#pragma unroll
      for (int ni = 0; ni < 4; ni++)
        acc[mi][ni] = __builtin_amdgcn_mfma_f32_16x16x32_bf16(af[mi], bfr[ni], acc[mi][ni], 0, 0, 0);
    __syncthreads();
  }

  // ---- register epilogue: per-row max/argmax/sum-exp over this block's 128 cols ----
  // acc[mi][ni][q] is (row = wr*64+mi*16+lg*4+q, col = wc*64+ni*16+l15)
  const int colb = cb * 128 + wc * 64;
#pragma unroll
  for (int mi = 0; mi < 4; mi++) {
    int x1q[4];
#pragma unroll
    for (int q = 0; q < 4; q++) x1q[q] = sx1[wr * 64 + mi * 16 + lg * 4 + q];
#pragma unroll
    for (int q = 0; q < 4; q++) {
      const int rl = wr * 64 + mi * 16 + lg * 4 + q;
      // pass 1: max + argmax (first-index)
      float m = NEGINF; int amx = 0x7fffffff;
#pragma unroll
      for (int ni = 0; ni < 4; ni++) {
        float x = acc[mi][ni][q];
        int colg = colb + ni * 16 + l15;
        if (colg == x1q[q]) tgt[rb * 128 + rl] = x;
        if (colg < VOCAB && x > m) { m = x; amx = colg; }
      }
#pragma unroll
      for (int d = 1; d < 16; d <<= 1) {
        float om = __shfl_xor(m, d, 64);
        int oa = __shfl_xor(amx, d, 64);
        amx = (m > om) ? amx : ((om > m) ? oa : min(amx, oa));
        m = fmaxf(m, om);
      }
      // pass 2: sum exp(x - m)
      float s = 0.0f;
#pragma unroll
      for (int ni = 0; ni < 4; ni++) {
        float x = acc[mi][ni][q];
        int colg = colb + ni * 16 + l15;
        if (colg < VOCAB) s += __expf(x - m);
      }
#pragma unroll
      for (int d = 1; d < 16; d <<= 1) s += __shfl_xor(s, d, 64);
      if (l15 == 0) { rm_[rl][wc] = m; rs_[rl][wc] = s; ri_[rl][wc] = amx; }
    }
  }
  __syncthreads();
  if (tid < 128) {
    float m0 = rm_[tid][0], s0 = rs_[tid][0]; int a0 = ri_[tid][0];
    float m1 = rm_[tid][1], s1 = rs_[tid][1]; int a1 = ri_[tid][1];
    float M = fmaxf(m0, m1);
    float S = s0 * __expf(m0 - M) + s1 * __expf(m1 - M);
    int A2 = (m0 > m1) ? a0 : ((m1 > m0) ? a1 : min(a0, a1));
    int rowg = rb * 128 + tid;
    size_t pidx = (size_t)rowg * NCB + cb;
    pm[pidx] = M; ps[pidx] = S; pi[pidx] = A2;
  }
}

// ---- kernel 4a: combine NCB partials per row -> nll + hit ----
__global__ __launch_bounds__(256) void k_rowreduce(const float* __restrict__ pm,
                                                   const float* __restrict__ ps,
                                                   const int* __restrict__ pi,
                                                   const float* __restrict__ tgt,
                                                   const int* __restrict__ x1_arr,
                                                   float* __restrict__ rownll,
                                                   float* __restrict__ rowhit) {
  const int row = blockIdx.x, tid = threadIdx.x;
  float M = NEGINF, S = 0.0f; int best = 0x7fffffff;
  for (int cbk = tid; cbk < NCB; cbk += 256) {
    size_t pidx = (size_t)row * NCB + cbk;
    float m = pm[pidx], sv = ps[pidx]; int idx = pi[pidx];
    if (m > M) { S = S * __expf(M - m) + sv; M = m; best = idx; }
    else if (m == M) { S += sv; if (idx < best) best = idx; }
    else S += sv * __expf(m - M);
  }
  __shared__ float sm_[256], ss_[256]; __shared__ int si_[256];
  sm_[tid] = M; ss_[tid] = S; si_[tid] = best;
  __syncthreads();
  for (int off = 128; off > 0; off >>= 1) {
    if (tid < off) {
      float m2 = sm_[tid + off], s2 = ss_[tid + off]; int i2 = si_[tid + off];
      float M1 = sm_[tid], S1 = ss_[tid]; int b1 = si_[tid];
      float Mn = fmaxf(M1, m2);
      float Sn = S1 * __expf(M1 - Mn) + s2 * __expf(m2 - Mn);
      int bn = (M1 > m2) ? b1 : ((m2 > M1) ? i2 : ((b1 < i2) ? b1 : i2));
      sm_[tid] = Mn; ss_[tid] = Sn; si_[tid] = bn;
    }
    __syncthreads();
  }
  if (tid == 0) {
    float nll = sm_[0] + logf(ss_[0]) - tgt[row];
    rownll[row] = nll;
    rowhit[row] = (si_[0] == x1_arr[row]) ? 1.0f : 0.0f;
  }
}

// ---- kernel 4b: final means ----
__global__ __launch_bounds__(1024) void k_final(const float* __restrict__ rownll,
                                                const float* __restrict__ rowhit,
                                                float* __restrict__ out) {
  const int tid = threadIdx.x;
  float l = rownll[tid] + rownll[tid + 1024];
  float a = rowhit[tid] + rowhit[tid + 1024];
  __shared__ float sl[1024], sa[1024];
  sl[tid] = l; sa[tid] = a;
  __syncthreads();
  for (int off = 512; off > 0; off >>= 1) {
    if (tid < off) { sl[tid] += sl[tid + off]; sa[tid] += sa[tid + off]; }
    __syncthreads();
  }
  if (tid == 0) { out[0] = sl[0] * (1.0f / 2048.0f); out[1] = sa[0] * (1.0f / 2048.0f); }
}

extern "C" void kernel_launch(void* const* d_in, const int* in_sizes, int n_in,
                              void* d_out, int out_size, void* d_ws, size_t ws_size,
                              hipStream_t stream) {
  const int* x1 = (const int*)d_in[0];
  const float* t = (const float*)d_in[1];
  const float* emb = (const float*)d_in[2];
  const float* w_time = (const float*)d_in[3];
  const float* w_out = (const float*)d_in[4];
  float* out = (float*)d_out;

  char* ws = (char*)d_ws;
  int* xt = (int*)ws;                                              // 8 KB
  unsigned short* h = (unsigned short*)(ws + 8192);                // 1 MB
  unsigned short* wt = (unsigned short*)(ws + 8192 + 1048576);     // 25.73 MB
  size_t off = 8192 + 1048576 + (size_t)VOCAB * DMODEL * 2;        // 26,788,352
  float* pm = (float*)(ws + off);  off += (size_t)NROWS * NCB * 4;
  float* ps = (float*)(ws + off);  off += (size_t)NROWS * NCB * 4;
  int*   pi = (int*)(ws + off);    off += (size_t)NROWS * NCB * 4;
  float* tgt = (float*)(ws + off); off += NROWS * 4;
  float* rownll = (float*)(ws + off); off += NROWS * 4;
  float* rowhit = (float*)(ws + off); off += NROWS * 4;

  dim3 b256(256);
  k_sample<<<dim3(NROWS), b256, 0, stream>>>(x1, t, xt);
  k_h<<<dim3(NROWS), b256, 0, stream>>>(xt, t, emb, w_time, h);
  k_wt<<<dim3(786, 4), b256, 0, stream>>>(w_out, wt);
  k_gemm<<<dim3(16, NCB), b256, 0, stream>>>(h, wt, x1, pm, ps, pi, tgt);
  k_rowreduce<<<dim3(NROWS), b256, 0, stream>>>(pm, ps, pi, tgt, x1, rownll, rowhit);
  k_final<<<dim3(1), dim3(1024), 0, stream>>>(rownll, rowhit, out);
}

// Round 4
// 370.320 us; speedup vs baseline: 1.5218x; 1.0225x over previous
//
#include <hip/hip_runtime.h>
#include <hip/hip_bf16.h>
#include <stdint.h>

#define VOCAB 50257
#define DMODEL 256
#define NROWS 2048
#define NCB 393  /* ceil(50257/128) */
#define NEGINF (-3.0e38f)

typedef short bf16x8 __attribute__((ext_vector_type(8)));
typedef float f32x4 __attribute__((ext_vector_type(4)));

__device__ __forceinline__ uint32_t rotl32(uint32_t x, int d) {
  return __builtin_amdgcn_alignbit(x, x, (uint32_t)(32 - d));  // v_alignbit_b32: rotr(x,32-d)=rotl(x,d)
}

// ---- threefry2x32 with key = (0,1)  [jax.random.key(1)] ----
__device__ __forceinline__ void tf2x32(uint32_t x0, uint32_t x1, uint32_t& o0, uint32_t& o1) {
  const uint32_t K0 = 0u, K1 = 1u, K2 = 0x1BD11BDBu;  // 0^1^0x1BD11BDA
  x0 += K0; x1 += K1;
#define TFR(d) { x0 += x1; x1 = rotl32(x1, d); x1 ^= x0; }
  TFR(13) TFR(15) TFR(26) TFR(6)
  x0 += K1; x1 += K2 + 1u;
  TFR(17) TFR(29) TFR(16) TFR(24)
  x0 += K2; x1 += K0 + 2u;
  TFR(13) TFR(15) TFR(26) TFR(6)
  x0 += K0; x1 += K1 + 3u;
  TFR(17) TFR(29) TFR(16) TFR(24)
  x0 += K1; x1 += K2 + 4u;
  TFR(13) TFR(15) TFR(26) TFR(6)
  x0 += K2; x1 += K0 + 5u;
#undef TFR
  o0 = x0; o1 = x1;
}

// jax uniform(tiny,1) -> gumbel, from the 23-bit mantissa bits
__device__ __forceinline__ float gumbel_from_bits(uint32_t b23) {
  float f = __uint_as_float(b23 | 0x3f800000u) - 1.0f;
  float u = fmaxf(f, 1.17549435e-38f);
  return -logf(-logf(u));
}

__device__ __forceinline__ unsigned short f32_to_bf16_bits(float x) {
  __hip_bfloat16 b = __float2bfloat16(x);
  return __builtin_bit_cast(unsigned short, b);
}

// ---- kernel 1 (fused): blocks [0,2048) sample x_t; blocks [2048,5192) transpose w_out ----
// Sampler: branch-free max over ALL v of packed=(bits23, 511-it); x1 exclusion fixed up
// post-hoc (argmax==x1 -> xt=x1 is exact; else miss-max == global max).
__global__ __launch_bounds__(256) void k_pre(const int* __restrict__ x1_arr,
                                             const float* __restrict__ t_arr,
                                             int* __restrict__ xt_out,
                                             const float* __restrict__ w,
                                             unsigned short* __restrict__ wt) {
  __shared__ union {
    float tile[64][65];                       // transpose role (16.6 KB)
    struct { uint32_t p[256]; int t[256]; } r; // sampler reduce (2 KB)
  } u;
  const int tid = threadIdx.x;

  if (blockIdx.x >= NROWS) {
    // ---- w_out transpose role: wt[v][d] = bf16(w[d][v]) ----
    const int bid2 = blockIdx.x - NROWS;
    const int v0 = (bid2 % 786) * 64;
    const int d0 = (bid2 / 786) * 64;
#pragma unroll
    for (int i = 0; i < 16; i++) {
      int idx = i * 256 + tid;
      int dd = idx >> 6, vv = idx & 63;
      int v = v0 + vv;
      u.tile[dd][vv] = (v < VOCAB) ? w[(size_t)(d0 + dd) * VOCAB + v] : 0.0f;
    }
    __syncthreads();
#pragma unroll
    for (int i = 0; i < 16; i++) {
      int idx = i * 256 + tid;
      int vv = idx >> 6, dd = idx & 63;
      int v = v0 + vv;
      if (v < VOCAB) wt[(size_t)v * DMODEL + d0 + dd] = f32_to_bf16_bits(u.tile[dd][vv]);
    }
    return;
  }

  // ---- sampler role ----
  const int rr = blockIdx.x;
  const uint32_t ctr0 = (uint32_t)rr * (uint32_t)VOCAB + (uint32_t)tid;
  uint32_t pmax = 0u;
  const int FULL = VOCAB >> 8;  // 196
#pragma unroll 4
  for (int it = 0; it < FULL; ++it) {
    uint32_t o0, o1;
    tf2x32(0u, ctr0 + (uint32_t)(it << 8), o0, o1);
    pmax = max(pmax, ((o0 ^ o1) & 0xFFFFFE00u) | (uint32_t)(511 - it));
  }
  if (tid < (VOCAB - FULL * 256)) {  // tail: 81 lanes
    uint32_t o0, o1;
    tf2x32(0u, ctr0 + (uint32_t)(FULL << 8), o0, o1);
    pmax = max(pmax, ((o0 ^ o1) & 0xFFFFFE00u) | (uint32_t)(511 - FULL));
  }

  u.r.p[tid] = pmax; u.r.t[tid] = tid;
  __syncthreads();
  for (int off = 128; off > 0; off >>= 1) {
    if (tid < off) {
      uint32_t p2 = u.r.p[tid + off]; int t2 = u.r.t[tid + off];
      if (p2 > u.r.p[tid] || (p2 == u.r.p[tid] && t2 < u.r.t[tid])) { u.r.p[tid] = p2; u.r.t[tid] = t2; }
    }
    __syncthreads();
  }
  if (tid == 0) {
    const uint32_t packed = u.r.p[0];
    const int amax = ((511 - (int)(packed & 0x1FFu)) << 8) + u.r.t[0];
    const int x1 = x1_arr[rr];
    int xt;
    if (amax == x1) {
      xt = x1;  // global argmax is x1: score(x1) >= all (bits max + Lhit >= Lmiss)
    } else {
      const uint32_t bmax = packed >> 9;
      uint32_t o0, o1;
      tf2x32(0u, (uint32_t)rr * (uint32_t)VOCAB + (uint32_t)x1, o0, o1);
      const uint32_t bx1 = (o0 ^ o1) >> 9;
      float tv = t_arr[rr >> 10];               // batch = rr / T
      float pmiss = (1.0f - tv) / 50257.0f;
      float A = gumbel_from_bits(bx1) + logf(tv + pmiss);
      float Bv = gumbel_from_bits(bmax) + logf(pmiss);
      if (A > Bv) xt = x1;
      else if (A == Bv) xt = (x1 < amax) ? x1 : amax;  // first-index tie like jnp.argmax
      else xt = amax;
    }
    xt_out[rr] = xt;
  }
}

// ---- kernel 2: h_bf16[r][d] = bf16( emb[x_t[r]][d] + t_b * w_time[d] ) ----
__global__ __launch_bounds__(256) void k_h(const int* __restrict__ xt,
                                           const float* __restrict__ t_arr,
                                           const float* __restrict__ emb,
                                           const float* __restrict__ w_time,
                                           unsigned short* __restrict__ h_out) {
  const int rr = blockIdx.x, d = threadIdx.x;
  float tv = t_arr[rr >> 10];
  int e = xt[rr];
  float hv = emb[(size_t)e * DMODEL + d] + tv * w_time[d];
  h_out[rr * DMODEL + d] = f32_to_bf16_bits(hv);
}

// ---- kernel 3: logits tile GEMM (bf16 MFMA) + register-resident fused LSE/argmax ----
// grid(16 rb fast, 393 cb slow): blocks sharing a B-panel are concurrent; h stays L2-hot.
__global__ __launch_bounds__(256) void k_gemm(const unsigned short* __restrict__ h,
                                              const unsigned short* __restrict__ wt,
                                              const int* __restrict__ x1_arr,
                                              float* __restrict__ pm, float* __restrict__ ps,
                                              int* __restrict__ pi, float* __restrict__ tgt) {
  __shared__ unsigned short sa[128][40];  // stride 40 shorts = 20 banks -> uniform groups
  __shared__ unsigned short sb[128][40];
  __shared__ float rm_[128][2], rs_[128][2]; __shared__ int ri_[128][2];
  __shared__ int sx1[128];

  const int tid = threadIdx.x;
  const int rb = blockIdx.x, cb = blockIdx.y;
  const int lane = tid & 63;
  const int wid = tid >> 6;
  const int wr = wid >> 1, wc = wid & 1;   // 2x2 wave grid, 64x64 per wave
  const int l15 = lane & 15;
  const int lg = lane >> 4;
  const int lk = lg * 8;

  if (tid < 128) sx1[tid] = x1_arr[rb * 128 + tid];

  f32x4 acc[4][4] = {};

  const int rstage = tid >> 2;  // 0..63
  const int part = tid & 3;
  const int cg0 = cb * 128 + rstage;

  uint4 pa0, pa1, pb0, pb1;
  {
    pa0 = *reinterpret_cast<const uint4*>(h + ((size_t)(rb * 128 + rstage) * DMODEL + part * 8));
    pa1 = *reinterpret_cast<const uint4*>(h + ((size_t)(rb * 128 + rstage + 64) * DMODEL + part * 8));
    pb0 = make_uint4(0u, 0u, 0u, 0u); pb1 = make_uint4(0u, 0u, 0u, 0u);
    if (cg0 < VOCAB)      pb0 = *reinterpret_cast<const uint4*>(wt + ((size_t)cg0 * DMODEL + part * 8));
    if (cg0 + 64 < VOCAB) pb1 = *reinterpret_cast<const uint4*>(wt + ((size_t)(cg0 + 64) * DMODEL + part * 8));
  }

  for (int kc = 0; kc < 8; kc++) {
    *reinterpret_cast<uint4*>(&sa[rstage][part * 8]) = pa0;
    *reinterpret_cast<uint4*>(&sa[rstage + 64][part * 8]) = pa1;
    *reinterpret_cast<uint4*>(&sb[rstage][part * 8]) = pb0;
    *reinterpret_cast<uint4*>(&sb[rstage + 64][part * 8]) = pb1;
    __syncthreads();

    // prefetch next K-step ((kc+1)&7 wraps harmlessly on the last iter)
    {
      const int ko = ((kc + 1) & 7) * 32 + part * 8;
      pa0 = *reinterpret_cast<const uint4*>(h + ((size_t)(rb * 128 + rstage) * DMODEL + ko));
      pa1 = *reinterpret_cast<const uint4*>(h + ((size_t)(rb * 128 + rstage + 64) * DMODEL + ko));
      pb0 = make_uint4(0u, 0u, 0u, 0u); pb1 = make_uint4(0u, 0u, 0u, 0u);
      if (cg0 < VOCAB)      pb0 = *reinterpret_cast<const uint4*>(wt + ((size_t)cg0 * DMODEL + ko));
      if (cg0 + 64 < VOCAB) pb1 = *reinterpret_cast<const uint4*>(wt + ((size_t)(cg0 + 64) * DMODEL + ko));
    }

    bf16x8 af[4], bfr[4];
#pragma unroll
    for (int mi = 0; mi < 4; mi++)
      af[mi] = *reinterpret_cast<const bf16x8*>(&sa[wr * 64 + mi * 16 + l15][lk]);
#pragma unroll
    for (int ni = 0; ni < 4; ni++)
      bfr[ni] = *reinterpret_cast<const bf16x8*>(&sb[wc * 64 + ni * 16 + l15][lk]);
#pragma unroll
    for (int mi = 0; mi < 4; mi++)
#pragma unroll
      for (int ni = 0; ni < 4; ni++)
        acc[mi][ni] = __builtin_amdgcn_mfma_f32_16x16x32_bf16(af[mi], bfr[ni], acc[mi][ni], 0, 0, 0);
    __syncthreads();
  }

  // ---- register epilogue: per-row max/argmax/sum-exp over this block's 128 cols ----
  // acc[mi][ni][q] is (row = wr*64+mi*16+lg*4+q, col = wc*64+ni*16+l15)
  const int colb = cb * 128 + wc * 64;
#pragma unroll
  for (int mi = 0; mi < 4; mi++) {
    int x1q[4];
#pragma unroll
    for (int q = 0; q < 4; q++) x1q[q] = sx1[wr * 64 + mi * 16 + lg * 4 + q];
#pragma unroll
    for (int q = 0; q < 4; q++) {
      const int rl = wr * 64 + mi * 16 + lg * 4 + q;
      // pass 1: max + argmax (first-index)
      float m = NEGINF; int amx = 0x7fffffff;
#pragma unroll
      for (int ni = 0; ni < 4; ni++) {
        float x = acc[mi][ni][q];
        int colg = colb + ni * 16 + l15;
        if (colg == x1q[q]) tgt[rb * 128 + rl] = x;
        if (colg < VOCAB && x > m) { m = x; amx = colg; }
      }
#pragma unroll
      for (int d = 1; d < 16; d <<= 1) {
        float om = __shfl_xor(m, d, 64);
        int oa = __shfl_xor(amx, d, 64);
        amx = (m > om) ? amx : ((om > m) ? oa : min(amx, oa));
        m = fmaxf(m, om);
      }
      // pass 2: sum exp(x - m)
      float s = 0.0f;
#pragma unroll
      for (int ni = 0; ni < 4; ni++) {
        float x = acc[mi][ni][q];
        int colg = colb + ni * 16 + l15;
        if (colg < VOCAB) s += __expf(x - m);
      }
#pragma unroll
      for (int d = 1; d < 16; d <<= 1) s += __shfl_xor(s, d, 64);
      if (l15 == 0) { rm_[rl][wc] = m; rs_[rl][wc] = s; ri_[rl][wc] = amx; }
    }
  }
  __syncthreads();
  if (tid < 128) {
    float m0 = rm_[tid][0], s0 = rs_[tid][0]; int a0 = ri_[tid][0];
    float m1 = rm_[tid][1], s1 = rs_[tid][1]; int a1 = ri_[tid][1];
    float M = fmaxf(m0, m1);
    float S = s0 * __expf(m0 - M) + s1 * __expf(m1 - M);
    int A2 = (m0 > m1) ? a0 : ((m1 > m0) ? a1 : min(a0, a1));
    int rowg = rb * 128 + tid;
    size_t pidx = (size_t)rowg * NCB + cb;
    pm[pidx] = M; ps[pidx] = S; pi[pidx] = A2;
  }
}

// ---- kernel 4a: combine NCB partials per row -> nll + hit ----
__global__ __launch_bounds__(256) void k_rowreduce(const float* __restrict__ pm,
                                                   const float* __restrict__ ps,
                                                   const int* __restrict__ pi,
                                                   const float* __restrict__ tgt,
                                                   const int* __restrict__ x1_arr,
                                                   float* __restrict__ rownll,
                                                   float* __restrict__ rowhit) {
  const int row = blockIdx.x, tid = threadIdx.x;
  float M = NEGINF, S = 0.0f; int best = 0x7fffffff;
  for (int cbk = tid; cbk < NCB; cbk += 256) {
    size_t pidx = (size_t)row * NCB + cbk;
    float m = pm[pidx], sv = ps[pidx]; int idx = pi[pidx];
    if (m > M) { S = S * __expf(M - m) + sv; M = m; best = idx; }
    else if (m == M) { S += sv; if (idx < best) best = idx; }
    else S += sv * __expf(m - M);
  }
  __shared__ float sm_[256], ss_[256]; __shared__ int si_[256];
  sm_[tid] = M; ss_[tid] = S; si_[tid] = best;
  __syncthreads();
  for (int off = 128; off > 0; off >>= 1) {
    if (tid < off) {
      float m2 = sm_[tid + off], s2 = ss_[tid + off]; int i2 = si_[tid + off];
      float M1 = sm_[tid], S1 = ss_[tid]; int b1 = si_[tid];
      float Mn = fmaxf(M1, m2);
      float Sn = S1 * __expf(M1 - Mn) + s2 * __expf(m2 - Mn);
      int bn = (M1 > m2) ? b1 : ((m2 > M1) ? i2 : ((b1 < i2) ? b1 : i2));
      sm_[tid] = Mn; ss_[tid] = Sn; si_[tid] = bn;
    }
    __syncthreads();
  }
  if (tid == 0) {
    float nll = sm_[0] + logf(ss_[0]) - tgt[row];
    rownll[row] = nll;
    rowhit[row] = (si_[0] == x1_arr[row]) ? 1.0f : 0.0f;
  }
}

// ---- kernel 4b: final means ----
__global__ __launch_bounds__(1024) void k_final(const float* __restrict__ rownll,
                                                const float* __restrict__ rowhit,
                                                float* __restrict__ out) {
  const int tid = threadIdx.x;
  float l = rownll[tid] + rownll[tid + 1024];
  float a = rowhit[tid] + rowhit[tid + 1024];
  __shared__ float sl[1024], sa[1024];
  sl[tid] = l; sa[tid] = a;
  __syncthreads();
  for (int off = 512; off > 0; off >>= 1) {
    if (tid < off) { sl[tid] += sl[tid + off]; sa[tid] += sa[tid + off]; }
    __syncthreads();
  }
  if (tid == 0) { out[0] = sl[0] * (1.0f / 2048.0f); out[1] = sa[0] * (1.0f / 2048.0f); }
}

extern "C" void kernel_launch(void* const* d_in, const int* in_sizes, int n_in,
                              void* d_out, int out_size, void* d_ws, size_t ws_size,
                              hipStream_t stream) {
  const int* x1 = (const int*)d_in[0];
  const float* t = (const float*)d_in[1];
  const float* emb = (const float*)d_in[2];
  const float* w_time = (const float*)d_in[3];
  const float* w_out = (const float*)d_in[4];
  float* out = (float*)d_out;

  char* ws = (char*)d_ws;
  int* xt = (int*)ws;                                              // 8 KB
  unsigned short* h = (unsigned short*)(ws + 8192);                // 1 MB
  unsigned short* wt = (unsigned short*)(ws + 8192 + 1048576);     // 25.73 MB
  size_t off = 8192 + 1048576 + (size_t)VOCAB * DMODEL * 2;        // 26,788,352
  float* pm = (float*)(ws + off);  off += (size_t)NROWS * NCB * 4;
  float* ps = (float*)(ws + off);  off += (size_t)NROWS * NCB * 4;
  int*   pi = (int*)(ws + off);    off += (size_t)NROWS * NCB * 4;
  float* tgt = (float*)(ws + off); off += NROWS * 4;
  float* rownll = (float*)(ws + off); off += NROWS * 4;
  float* rowhit = (float*)(ws + off); off += NROWS * 4;

  dim3 b256(256);
  k_pre<<<dim3(NROWS + 3144), b256, 0, stream>>>(x1, t, xt, w_out, wt);
  k_h<<<dim3(NROWS), b256, 0, stream>>>(xt, t, emb, w_time, h);
  k_gemm<<<dim3(16, NCB), b256, 0, stream>>>(h, wt, x1, pm, ps, pi, tgt);
  k_rowreduce<<<dim3(NROWS), b256, 0, stream>>>(pm, ps, pi, tgt, x1, rownll, rowhit);
  k_final<<<dim3(1), dim3(1024), 0, stream>>>(rownll, rowhit, out);
}